// Round 6
// baseline (2016.277 us; speedup 1.0000x reference)
//
#include <hip/hip_runtime.h>

// Stacked LSTM (4 layers, units 100/80/50/30) + dense head, fp32, B=T=512.
//
// R5: occupancy-pinned, small-weight-slice redesign.
//   Evidence R1/R2/R3/R4: the pre-RA scheduler targets its OWN occupancy
//   (2 blocks/CU where possible), limiting register pressure below the
//   launch_bounds cap; the weight array then spills and is reloaded every
//   step (~144 extra ops/thread/step = the VALUBusy gap; PIN was a no-op
//   because spill-reload, not remat, is the mechanism).
//   Fix A: k-split widened (S=10..16) so per-thread weights are 24..72
//   floats -> demand fits even a 128-VGPR budget.
//   Fix B: __attribute__((amdgpu_waves_per_eu(min,max))) pins the
//   scheduler's occupancy target (launch_bounds can't set the max):
//   (4,4) for 1024-thread blocks, (2,2) for 512-thread blocks.
//   Bonus: 4 waves/SIMD doubles latency-hiding TLP.
//
//   Structure otherwise as R3/R4 (passed twice, absmax 7.6e-6):
//   - thread (p=tid%U, s=tid/U) owns all 4 gates of unit p, k-slice s.
//   - concat(h,x) rows interleaved {a_k,b_k}; ds_read_b128 broadcasts.
//   - z partials as packed float4 [s][row][u]; cell thread reduces S.
//   - two barriers/step; ping-pong buffers; x(t+1) prefetch (T14).
//   - all fp32 (no fp32 MFMA on CDNA4; bf16 risks the 4.4e-4 threshold).

#define T_SEQ 512
#define B_TOT 512

#define PIN(x) asm volatile("" : "+v"(x))

__device__ __forceinline__ float sigmoidf_(float x) {
    return 1.0f / (1.0f + __expf(-x));
}
__device__ __forceinline__ float tanh_fast(float x) {
    float e = __expf(2.0f * x);
    return 1.0f - 2.0f / (1.0f + e);   // saturates correctly at +-inf
}

// U: units, FI: input feats, S: k-slices, KH: k per slice (DIN4 = S*KH).
template<int U, int FI, int S, int KH, int BLOCK, int WMIN, int WMAX, bool SEQ, bool FINAL>
__global__ __launch_bounds__(BLOCK)
__attribute__((amdgpu_waves_per_eu(WMIN, WMAX)))
void lstm_layer(const float* __restrict__ X,    // [B][T][FI]
                const float* __restrict__ W,    // [DIN][4U] row-major
                const float* __restrict__ Bv,   // [4U] gate order f,i,g,o
                float* __restrict__ Hout,       // [B][T][U] if SEQ
                const float* __restrict__ Wd,   // [U] (FINAL)
                const float* __restrict__ bd,   // [1] (FINAL)
                float* __restrict__ OUT)        // [B] (FINAL)
{
    constexpr int DIN  = U + FI;
    constexpr int DIN4 = S * KH;
    static_assert(DIN4 >= DIN, "k-padding must cover DIN");
    static_assert((KH & 1) == 0, "KH even: one float4 = 2 k x 2 rows");
    constexpr int G  = 4 * U;
    constexpr int NT = S * U;
    static_assert(NT <= BLOCK, "GEMV threads must fit");
    static_assert(NT >= 2 * FI, "prefetch threads must be GEMV threads");
    constexpr int TOT = 2 * DIN4;

    __shared__ __align__(16) float buf[2][TOT];       // {a_k,b_k} interleaved
    __shared__ __align__(16) float zp[S * 2 * U * 4]; // [s][row][u][gate]

    const int tid = threadIdx.x;
    const int bb  = blockIdx.x * 2;      // two batch rows per block

    const int p = tid % U;               // unit
    const int s = tid / U;               // k-slice (GEMV threads: tid < NT)

    // ---- weights into registers (once; reused 512 steps) ----
    float w[4][KH];
    if (tid < NT) {
        #pragma unroll
        for (int g = 0; g < 4; ++g) {
            #pragma unroll
            for (int kk = 0; kk < KH; ++kk) {
                const int k = s * KH + kk;
                w[g][kk] = (k < DIN) ? W[(size_t)k * G + g * U + p] : 0.0f;
            }
        }
        #pragma unroll
        for (int g = 0; g < 4; ++g) {
            #pragma unroll
            for (int kk = 0; kk < KH; ++kk) PIN(w[g][kk]);
        }
    }

    // ---- cell threads: tid < 2U -> (u = p, r = s in {0,1}) ----
    float cb4[4] = {0.f, 0.f, 0.f, 0.f};
    if (tid < 2 * U) {
        #pragma unroll
        for (int g = 0; g < 4; ++g) cb4[g] = Bv[g * U + p];
    }
    float hreg = 0.0f, creg = 0.0f;
    float wdreg = 0.0f;
    if constexpr (FINAL) { if (tid < 2 * U) wdreg = Wd[p]; }

    // ---- x-prefetch mapping (tid < 2*FI, all are GEMV threads) ----
    const int xr = (tid < FI) ? 0 : 1;
    const int xj = tid - xr * FI;
    const float* Xrow = X + (size_t)(bb + xr) * T_SEQ * FI + xj;
    const int xwi = 2 * (U + xj) + xr;

    // ---- init: zero both buffers (h=0 + k-pad), stage x(0) ----
    for (int i = tid; i < 2 * TOT; i += BLOCK) ((float*)buf)[i] = 0.0f;
    __syncthreads();
    if (tid < 2 * FI) buf[0][xwi] = Xrow[0];
    __syncthreads();

    const int rbase = s * (KH / 2);      // per-lane f4 read base

    for (int t = 0; t < T_SEQ; ++t) {
        const int cur = t & 1, nxt = cur ^ 1;

        // prefetch x(t+1) global->reg; retires under the GEMV
        float xpre = 0.0f;
        const bool do_x = (tid < 2 * FI) && (t + 1 < T_SEQ);
        if (do_x) xpre = Xrow[(size_t)(t + 1) * FI];

        // ---- phase 1: GEMV partials ----
        if (tid < NT) {
            float a0 = 0.f, a1 = 0.f, a2 = 0.f, a3 = 0.f;   // row 0, gates f,i,g,o
            float b0 = 0.f, b1 = 0.f, b2 = 0.f, b3 = 0.f;   // row 1
            const float4* rb = (const float4*)buf[cur];
            #pragma unroll
            for (int q = 0; q < KH / 2; ++q) {
                const float4 v = rb[rbase + q];  // {a(2q), b(2q), a(2q+1), b(2q+1)}
                a0 += w[0][2*q] * v.x; b0 += w[0][2*q] * v.y;
                a1 += w[1][2*q] * v.x; b1 += w[1][2*q] * v.y;
                a2 += w[2][2*q] * v.x; b2 += w[2][2*q] * v.y;
                a3 += w[3][2*q] * v.x; b3 += w[3][2*q] * v.y;
                a0 += w[0][2*q+1] * v.z; b0 += w[0][2*q+1] * v.w;
                a1 += w[1][2*q+1] * v.z; b1 += w[1][2*q+1] * v.w;
                a2 += w[2][2*q+1] * v.z; b2 += w[2][2*q+1] * v.w;
                a3 += w[3][2*q+1] * v.z; b3 += w[3][2*q+1] * v.w;
            }
            float4* zq = (float4*)zp;
            zq[(s * 2 + 0) * U + p] = make_float4(a0, a1, a2, a3);
            zq[(s * 2 + 1) * U + p] = make_float4(b0, b1, b2, b3);
        }
        // stage x(t+1) reg->LDS (disjoint region from phase-2 h writes)
        if (do_x) buf[nxt][xwi] = xpre;
        __syncthreads();

        // ---- phase 2: reduce + cell update ----
        if (tid < 2 * U) {
            float z0 = cb4[0], z1 = cb4[1], z2 = cb4[2], z3 = cb4[3];
            const float4* zq = (const float4*)zp;
            #pragma unroll
            for (int ss = 0; ss < S; ++ss) {
                const float4 v = zq[(ss * 2 + s) * U + p];
                z0 += v.x; z1 += v.y; z2 += v.z; z3 += v.w;
            }
            const float F  = sigmoidf_(z0);
            const float I  = sigmoidf_(z1);
            const float Gv = tanh_fast(z2);
            const float O  = sigmoidf_(z3);
            creg = F * creg + I * Gv;
            hreg = O * tanh_fast(creg);
            buf[nxt][2 * p + s] = hreg;
            if constexpr (SEQ) {
                Hout[((size_t)(bb + s) * T_SEQ + t) * U + p] = hreg;
            }
        }
        __syncthreads();
    }

    if constexpr (FINAL) {
        if (tid < 2 * U) buf[0][2 * p + s] = hreg * wdreg;
        __syncthreads();
        if (tid < 2) {
            float acc = bd[0];
            for (int u = 0; u < U; ++u) acc += buf[0][2 * u + tid];
            OUT[bb + tid] = acc;
        }
    }
}

extern "C" void kernel_launch(void* const* d_in, const int* in_sizes, int n_in,
                              void* d_out, int out_size, void* d_ws, size_t ws_size,
                              hipStream_t stream)
{
    const float* x    = (const float*)d_in[0];
    const float* W0   = (const float*)d_in[1];
    const float* b0   = (const float*)d_in[2];
    const float* W1   = (const float*)d_in[3];
    const float* b1   = (const float*)d_in[4];
    const float* W2   = (const float*)d_in[5];
    const float* b2   = (const float*)d_in[6];
    const float* W3   = (const float*)d_in[7];
    const float* b3   = (const float*)d_in[8];
    const float* Wout = (const float*)d_in[9];
    const float* bout = (const float*)d_in[10];
    float* out = (float*)d_out;

    float* H0 = (float*)d_ws;                         // [512*512*100]
    float* H1 = H0 + (size_t)B_TOT * T_SEQ * 100;     // [512*512*80]
    float* H2 = (float*)d_ws;                         // reuses H0 slot

    const dim3 grid(B_TOT / 2);

    // <U, FI, S, KH, BLOCK, WMIN, WMAX, SEQ, FINAL>
    // 1024-thr blocks: 16 waves = 4/EU exactly -> waves_per_eu(4,4), cap 128,
    //   per-thread weights 72/64 floats -> resident with headroom.
    // 512-thr blocks: 8 waves = 2/EU -> waves_per_eu(2,2), weights 56/24.
    hipLaunchKernelGGL((lstm_layer<100,  64, 10, 18, 1024, 4, 4, true,  false>),
                       grid, dim3(1024), 0, stream, x,  W0, b0, H0, nullptr, nullptr, nullptr);
    hipLaunchKernelGGL((lstm_layer< 80, 100, 12, 16, 1024, 4, 4, true,  false>),
                       grid, dim3(1024), 0, stream, H0, W1, b1, H1, nullptr, nullptr, nullptr);
    hipLaunchKernelGGL((lstm_layer< 50,  80, 10, 14,  512, 2, 2, true,  false>),
                       grid, dim3(512), 0, stream, H1, W2, b2, H2, nullptr, nullptr, nullptr);
    hipLaunchKernelGGL((lstm_layer< 30,  50, 16,  6,  512, 2, 2, false, true >),
                       grid, dim3(512), 0, stream, H2, W3, b3, nullptr, Wout, bout, out);
}

// Round 8
// 1932.771 us; speedup vs baseline: 1.0432x; 1.0432x over previous
//
#include <hip/hip_runtime.h>

// Stacked LSTM (4 layers, units 100/80/50/30) + dense head, fp32, B=T=512.
//
// R7: defeat the occupancy heuristic via LDS, keep weights in ARCH VGPRs.
//   Round 0-6 synthesis:
//   - RA hard cap from launch_bounds(512,2) is 256 arch VGPRs, BUT the
//     machine scheduler sets its pressure target from ACHIEVABLE occupancy
//     (incl. LDS): 18.9KB LDS -> 2 WGs/CU fit -> target 16 waves/CU ->
//     pressure target ~128 -> the 136-float weight array spills to AGPRs,
//     and gfx950 VALU CANNOT read AGPRs directly (R6 assembler error), so
//     every use pays v_accvgpr_read -> the measured ~1.8x VALU inflation.
//   Fix: pad static LDS to ~99KB so only ONE workgroup/CU fits by LDS
//   (160KB pool; 128KB static LDS proven on gfx950). Achievable occupancy
//   becomes 8 waves/CU = 2/EU -> scheduler pressure target ~256 -> weights
//   stay in arch VGPRs. Grid is 256 blocks on 256 CUs, so real occupancy
//   is unchanged.
//
//   Structure as R3/R4 (passed twice, absmax 7.6e-6):
//   - thread (p=tid%U, s=tid/U) owns all 4 gates of unit p, k-slice s.
//   - concat(h,x) rows interleaved {a_k,b_k}; group-uniform ds_read_b128
//     broadcasts (s-major thread order).
//   - z partials as packed float4 [s][row][u]; cell thread reduces S.
//   - two barriers/step; ping-pong buffers; x(t+1) prefetch (T14).
//   - all fp32 (no fp32 MFMA on CDNA4; bf16 risks the 4.4e-4 threshold).

#define T_SEQ 512
#define B_TOT 512
#define PADF  20480   // 80KB LDS pad -> total ~99KB -> 1 WG/CU by LDS

#define PIN(x) asm volatile("" : "+v"(x))

__device__ __forceinline__ float sigmoidf_(float x) {
    return 1.0f / (1.0f + __expf(-x));
}
__device__ __forceinline__ float tanh_fast(float x) {
    float e = __expf(2.0f * x);
    return 1.0f - 2.0f / (1.0f + e);   // saturates correctly at +-inf
}

// U: units, FI: input feats, S: k-slices, KH: k per slice (DIN4 = S*KH).
template<int U, int FI, int S, int KH, int BLOCK, bool SEQ, bool FINAL>
__global__ __launch_bounds__(BLOCK, 2)
void lstm_layer(const float* __restrict__ X,    // [B][T][FI]
                const float* __restrict__ W,    // [DIN][4U] row-major
                const float* __restrict__ Bv,   // [4U] gate order f,i,g,o
                float* __restrict__ Hout,       // [B][T][U] if SEQ
                const float* __restrict__ Wd,   // [U] (FINAL)
                const float* __restrict__ bd,   // [1] (FINAL)
                float* __restrict__ OUT)        // [B] (FINAL)
{
    constexpr int DIN  = U + FI;
    constexpr int DIN4 = S * KH;
    static_assert(DIN4 >= DIN, "k-padding must cover DIN");
    static_assert((KH & 1) == 0, "KH even: one float4 = 2 k x 2 rows");
    constexpr int G  = 4 * U;
    constexpr int NT = S * U;
    static_assert(NT <= BLOCK, "GEMV threads must fit");
    static_assert(NT >= 2 * FI, "prefetch threads must be GEMV threads");
    constexpr int TOT = 2 * DIN4;

    __shared__ __align__(16) float buf[2][TOT];       // {a_k,b_k} interleaved
    __shared__ __align__(16) float zp[S * 2 * U * 4]; // [s][row][u][gate]
    __shared__ float occ_pad[PADF];                   // occupancy limiter (see header)

    const int tid = threadIdx.x;
    const int bb  = blockIdx.x * 2;      // two batch rows per block

    const int p = tid % U;               // unit
    const int s = tid / U;               // k-slice (GEMV threads: tid < NT)

    // touch the pad so it cannot be eliminated (volatile, once, ~40 stores)
    for (int i = tid; i < PADF; i += BLOCK) ((volatile float*)occ_pad)[i] = 0.0f;

    // ---- weights into registers (once; reused 512 steps) ----
    float w[4][KH];
    if (tid < NT) {
        #pragma unroll
        for (int g = 0; g < 4; ++g) {
            #pragma unroll
            for (int kk = 0; kk < KH; ++kk) {
                const int k = s * KH + kk;
                w[g][kk] = (k < DIN) ? W[(size_t)k * G + g * U + p] : 0.0f;
            }
        }
        #pragma unroll
        for (int g = 0; g < 4; ++g) {
            #pragma unroll
            for (int kk = 0; kk < KH; ++kk) PIN(w[g][kk]);
        }
    }

    // ---- cell threads: tid < 2U -> (u = p, r = s in {0,1}) ----
    float cb4[4] = {0.f, 0.f, 0.f, 0.f};
    if (tid < 2 * U) {
        #pragma unroll
        for (int g = 0; g < 4; ++g) cb4[g] = Bv[g * U + p];
    }
    float hreg = 0.0f, creg = 0.0f;
    float wdreg = 0.0f;
    if constexpr (FINAL) { if (tid < 2 * U) wdreg = Wd[p]; }

    // ---- x-prefetch mapping (tid < 2*FI, all are GEMV threads) ----
    const int xr = (tid < FI) ? 0 : 1;
    const int xj = tid - xr * FI;
    const float* Xrow = X + (size_t)(bb + xr) * T_SEQ * FI + xj;
    const int xwi = 2 * (U + xj) + xr;

    // ---- init: zero both buffers (h=0 + k-pad), stage x(0) ----
    for (int i = tid; i < 2 * TOT; i += BLOCK) ((float*)buf)[i] = 0.0f;
    __syncthreads();
    if (tid < 2 * FI) buf[0][xwi] = Xrow[0];
    __syncthreads();

    const int rbase = s * (KH / 2);      // per-lane f4 read base

    for (int t = 0; t < T_SEQ; ++t) {
        const int cur = t & 1, nxt = cur ^ 1;

        // prefetch x(t+1) global->reg; retires under the GEMV
        float xpre = 0.0f;
        const bool do_x = (tid < 2 * FI) && (t + 1 < T_SEQ);
        if (do_x) xpre = Xrow[(size_t)(t + 1) * FI];

        // ---- phase 1: GEMV partials ----
        if (tid < NT) {
            float a0 = 0.f, a1 = 0.f, a2 = 0.f, a3 = 0.f;   // row 0: f,i,g,o
            float b0 = 0.f, b1 = 0.f, b2 = 0.f, b3 = 0.f;   // row 1
            const float4* rb = (const float4*)buf[cur];
            #pragma unroll
            for (int q = 0; q < KH / 2; ++q) {
                const float4 v = rb[rbase + q];  // {a(2q), b(2q), a(2q+1), b(2q+1)}
                a0 += w[0][2*q] * v.x; b0 += w[0][2*q] * v.y;
                a1 += w[1][2*q] * v.x; b1 += w[1][2*q] * v.y;
                a2 += w[2][2*q] * v.x; b2 += w[2][2*q] * v.y;
                a3 += w[3][2*q] * v.x; b3 += w[3][2*q] * v.y;
                a0 += w[0][2*q+1] * v.z; b0 += w[0][2*q+1] * v.w;
                a1 += w[1][2*q+1] * v.z; b1 += w[1][2*q+1] * v.w;
                a2 += w[2][2*q+1] * v.z; b2 += w[2][2*q+1] * v.w;
                a3 += w[3][2*q+1] * v.z; b3 += w[3][2*q+1] * v.w;
            }
            float4* zq = (float4*)zp;
            zq[(s * 2 + 0) * U + p] = make_float4(a0, a1, a2, a3);
            zq[(s * 2 + 1) * U + p] = make_float4(b0, b1, b2, b3);
        }
        // stage x(t+1) reg->LDS (disjoint region from phase-2 h writes)
        if (do_x) buf[nxt][xwi] = xpre;
        __syncthreads();

        // ---- phase 2: reduce + cell update ----
        if (tid < 2 * U) {
            float z0 = cb4[0], z1 = cb4[1], z2 = cb4[2], z3 = cb4[3];
            const float4* zq = (const float4*)zp;
            #pragma unroll
            for (int ss = 0; ss < S; ++ss) {
                const float4 v = zq[(ss * 2 + s) * U + p];
                z0 += v.x; z1 += v.y; z2 += v.z; z3 += v.w;
            }
            const float F  = sigmoidf_(z0);
            const float I  = sigmoidf_(z1);
            const float Gv = tanh_fast(z2);
            const float O  = sigmoidf_(z3);
            creg = F * creg + I * Gv;
            hreg = O * tanh_fast(creg);
            buf[nxt][2 * p + s] = hreg;
            if constexpr (SEQ) {
                Hout[((size_t)(bb + s) * T_SEQ + t) * U + p] = hreg;
            }
        }
        __syncthreads();
    }

    if constexpr (FINAL) {
        if (tid < 2 * U) buf[0][2 * p + s] = hreg * wdreg;
        __syncthreads();
        if (tid < 2) {
            float acc = bd[0];
            for (int u = 0; u < U; ++u) acc += buf[0][2 * u + tid];
            OUT[bb + tid] = acc;
        }
    }
}

extern "C" void kernel_launch(void* const* d_in, const int* in_sizes, int n_in,
                              void* d_out, int out_size, void* d_ws, size_t ws_size,
                              hipStream_t stream)
{
    const float* x    = (const float*)d_in[0];
    const float* W0   = (const float*)d_in[1];
    const float* b0   = (const float*)d_in[2];
    const float* W1   = (const float*)d_in[3];
    const float* b1   = (const float*)d_in[4];
    const float* W2   = (const float*)d_in[5];
    const float* b2   = (const float*)d_in[6];
    const float* W3   = (const float*)d_in[7];
    const float* b3   = (const float*)d_in[8];
    const float* Wout = (const float*)d_in[9];
    const float* bout = (const float*)d_in[10];
    float* out = (float*)d_out;

    float* H0 = (float*)d_ws;                         // [512*512*100]
    float* H1 = H0 + (size_t)B_TOT * T_SEQ * 100;     // [512*512*80]
    float* H2 = (float*)d_ws;                         // reuses H0 slot

    const dim3 grid(B_TOT / 2);

    // <U, FI, S, KH, BLOCK, SEQ, FINAL>
    // All 512-thread blocks (8 waves). Big static LDS -> 1 WG/CU by LDS ->
    // scheduler pressure target ~256 regs -> weight arrays (136/120/56/24
    // floats) resident in ARCH VGPRs.
    hipLaunchKernelGGL((lstm_layer<100,  64,  5, 34, 512, true,  false>),
                       grid, dim3(512), 0, stream, x,  W0, b0, H0, nullptr, nullptr, nullptr);
    hipLaunchKernelGGL((lstm_layer< 80, 100,  6, 30, 512, true,  false>),
                       grid, dim3(512), 0, stream, H0, W1, b1, H1, nullptr, nullptr, nullptr);
    hipLaunchKernelGGL((lstm_layer< 50,  80, 10, 14, 512, true,  false>),
                       grid, dim3(512), 0, stream, H1, W2, b2, H2, nullptr, nullptr, nullptr);
    hipLaunchKernelGGL((lstm_layer< 30,  50, 16,  6, 512, false, true >),
                       grid, dim3(512), 0, stream, H2, W3, b3, nullptr, Wout, bout, out);
}